// Round 7
// baseline (333.714 us; speedup 1.0000x reference)
//
#include <hip/hip_runtime.h>

#define NB 256              // histogram bins
#define NCH 48              // B*C = 16*3
#define HW (1024*1024)      // elements per channel
#define WPC (HW / 4)        // packed words per channel = 262144
#define THREADS 256
#define BPC 64              // blocks per channel -> 3072 blocks per big kernel
#define N4 (WPC / BPC)      // packed words per block = 4096
#define NTILE (N4 / (4 * THREADS))   // 4 uint4-tiles of 1024 words per block
#define HCOL 16             // histogram/LUT replication columns (16 KB LDS)

// Native clang vector types: __builtin_nontemporal_* rejects
// HIP_vector_type, but accepts ext_vector_type.
typedef float  nf4 __attribute__((ext_vector_type(4)));

// R7: R6 structure + bank-column-replicated LDS histogram (K1) and LUT (K3).
//   R6 post-mortem: controllable region ~112 us vs ~85 us floor. Remaining
//   slack = LDS pipe serialization on random bins: old layout put bin b in
//   bank b%32, so 64 lanes hashing random bins gave ~4-6-way worst-bank
//   conflicts on every DS atomic (K1) and every lut gather (K3)
//   (7.37M SQ_LDS_BANK_CONFLICT in the fused ancestor).
//   Fix: 16 replicated columns, bin-major: arr[bin*16 + (t&15)].
//   Bank = (bin&1)*16 + (t&15): only lanes t, t+16, t+32, t+48 can share a
//   bank, split across 2 banks by bin parity -> expected ~2 lanes/bank
//   (free per HW measurement), worst 4. 16 KB/block keeps 8 blocks/CU.

__device__ __forceinline__ int quant255(float v) {
    v = fminf(fmaxf(v, 0.0f), 1.0f);
    int q = (int)(v * 255.0f);     // fp32 mul + trunc, same as jnp
    q = q < 0 ? 0 : q;
    q = q > 255 ? 255 : q;
    return q;
}

// ---------------- K1: quantize + replicated LDS hist -> global hist -------
__global__ __launch_bounds__(THREADS, 8) void hist_quant_kernel(
    const float* __restrict__ x, unsigned int* __restrict__ ghist,
    unsigned int* __restrict__ q) {
    __shared__ unsigned int lh[NB * HCOL];   // 16 KB, bin-major x 16 columns
    const int t   = threadIdx.x;
    const int col = t & (HCOL - 1);
    for (int i = t; i < NB * HCOL; i += THREADS) lh[i] = 0u;
    __syncthreads();

    const int ch  = blockIdx.x / BPC;
    const int blk = blockIdx.x % BPC;
    const nf4* xp = (const nf4*)x + (size_t)ch * WPC;
    unsigned int* qp = q + (size_t)ch * WPC;
    const int base = blk * N4;

    for (int tile = 0; tile < NTILE; ++tile) {
        const int tb = base + tile * (4 * THREADS);
        unsigned pw[4];
        #pragma unroll
        for (int k = 0; k < 4; ++k) {
            // nontemporal: x is read exactly once across the whole pipeline
            nf4 v = __builtin_nontemporal_load(xp + tb + k * THREADS + t);
            int q0 = quant255(v.x), q1 = quant255(v.y);
            int q2 = quant255(v.z), q3 = quant255(v.w);
            atomicAdd(&lh[q0 * HCOL + col], 1u);
            atomicAdd(&lh[q1 * HCOL + col], 1u);
            atomicAdd(&lh[q2 * HCOL + col], 1u);
            atomicAdd(&lh[q3 * HCOL + col], 1u);
            pw[k] = (unsigned)q0 | ((unsigned)q1 << 8)
                  | ((unsigned)q2 << 16) | ((unsigned)q3 << 24);
        }
        // one 16 B unit-stride CACHEABLE store: q should stay L3-resident
        ((uint4*)(qp + tb))[t] = make_uint4(pw[0], pw[1], pw[2], pw[3]);
    }
    __syncthreads();

    // Reduce 16 columns of bin t (rotated start to spread banks; runs once)
    unsigned int s = 0;
    #pragma unroll
    for (int c = 0; c < HCOL; ++c)
        s += lh[t * HCOL + ((c + t) & (HCOL - 1))];
    if (s) atomicAdd(&ghist[ch * NB + t], s);
}

// ---------------- K3: scan ghist + replicated-LUT remap q -> y ------------
__global__ __launch_bounds__(THREADS, 8) void remap_kernel(
    const unsigned int* __restrict__ q, const unsigned int* __restrict__ ghist,
    float* __restrict__ y) {
    __shared__ float sbuf[NB];
    __shared__ float lutr[NB * HCOL];    // 16 KB, bin-major x 16 columns
    const int t   = threadIdx.x;
    const int col = t & (HCOL - 1);
    const int ch  = blockIdx.x / BPC;
    const int blk = blockIdx.x % BPC;

    // Per-block CDF scan (256 ints, L2-hot; ints < 2^24 -> exact fp32)
    sbuf[t] = (float)ghist[ch * NB + t];
    __syncthreads();
    for (int off = 1; off < NB; off <<= 1) {
        float add = (t >= off) ? sbuf[t - off] : 0.0f;
        __syncthreads();
        sbuf[t] += add;
        __syncthreads();
    }
    float total = sbuf[NB - 1];
    float lv = sbuf[t] / fmaxf(total, 1.0f);
    // Broadcast bin t's LUT value into all 16 columns (rotated; runs once)
    #pragma unroll
    for (int c = 0; c < HCOL; ++c)
        lutr[t * HCOL + ((c + t) & (HCOL - 1))] = lv;
    __syncthreads();

    const unsigned int* qp = q + (size_t)ch * WPC;
    nf4*                yp = (nf4*)y + (size_t)ch * WPC;
    const int base = blk * N4;

    for (int tile = 0; tile < NTILE; ++tile) {
        const int tb = base + tile * (4 * THREADS);
        uint4 pk = ((const uint4*)(qp + tb))[t];   // cacheable: L3 hit
        unsigned pw[4] = {pk.x, pk.y, pk.z, pk.w};
        #pragma unroll
        for (int k = 0; k < 4; ++k) {
            unsigned p = pw[k];
            nf4 o;
            o.x = lutr[(p & 255)         * HCOL + col];
            o.y = lutr[((p >> 8) & 255)  * HCOL + col];
            o.z = lutr[((p >> 16) & 255) * HCOL + col];
            o.w = lutr[(p >> 24)         * HCOL + col];
            // nontemporal: y is write-once, stream past L3
            __builtin_nontemporal_store(o, yp + tb + k * THREADS + t);
        }
    }
}

extern "C" void kernel_launch(void* const* d_in, const int* in_sizes, int n_in,
                              void* d_out, int out_size, void* d_ws, size_t ws_size,
                              hipStream_t stream) {
    const float* x = (const float*)d_in[0];
    float* y = (float*)d_out;

    unsigned int* ghist = (unsigned int*)d_ws;                        // 48 KB
    unsigned int* q     = (unsigned int*)((char*)d_ws + 256 * 1024);  // 48 MB

    // zero ghist (ws is 0xAA-poisoned before every launch)
    (void)hipMemsetAsync(d_ws, 0, 48 * 1024, stream);

    hist_quant_kernel<<<NCH * BPC, THREADS, 0, stream>>>(x, ghist, q);
    remap_kernel     <<<NCH * BPC, THREADS, 0, stream>>>(q, ghist, y);
}